// Round 2
// baseline (2208.272 us; speedup 1.0000x reference)
//
#include <hip/hip_runtime.h>

// Fused 2-layer GRU scan, persistent kernel, single-barrier pipelined.
// B=256,T=1024,F=64,U=128. 16 blocks x 512 threads; block owns 16 batch rows.
// Layer 2 runs ONE STEP DELAYED: iter t computes h1(t) (from h1(t-1)) and
// h2(t-1) (from h1(t-1), h2(t-2)) -> all LDS reads are pre-barrier state ->
// ONE __syncthreads per iter. Layer1-U1 and Layer2-W2 share the same h1(t-1)
// A-frags (read once). x A-frags come straight from global (L1), prefetched
// one iter ahead; all weight B-frags register/AGPR resident.

#define TT 1024
#define FF 64
#define G3 384

typedef __attribute__((ext_vector_type(8))) __bf16 bf16x8;
typedef __attribute__((ext_vector_type(4))) float f32x4;

#define MFMA(a, b, c) __builtin_amdgcn_mfma_f32_16x16x32_bf16((a), (b), (c), 0, 0, 0)

__device__ __forceinline__ float sigf(float x) { return 1.0f / (1.0f + __expf(-x)); }

__global__ __launch_bounds__(512, 2) void gru_fused(
    const float* __restrict__ x,   // [B,T,F]
    const float* __restrict__ W1,  // [F,3U]
    const float* __restrict__ U1,  // [U,3U]
    const float* __restrict__ b1,  // [2,3U]
    const float* __restrict__ W2,  // [U,3U]
    const float* __restrict__ U2,  // [U,3U]
    const float* __restrict__ b2,  // [2,3U]
    float* __restrict__ out)       // [x(256x128), state1, state2] fp32
{
    const int tid  = threadIdx.x;
    const int wave = tid >> 6;
    const int lane = tid & 63;
    const int quad = lane >> 4;
    const int lc   = lane & 15;         // A row / C col index
    const int u    = wave * 16 + lc;    // unit column (0..127)
    const int row0 = blockIdx.x * 16;

    // LDS: only h state, double-buffered. stride 136 (17x8): b128-aligned,
    // read pattern banks perfectly balanced (4(lc+quad) mod 32).
    __shared__ __align__(16) __bf16 h1s[2][16][136];
    __shared__ __align__(16) __bf16 h2s[2][16][136];

    for (int i = tid; i < 2 * 16 * 136; i += 512) {
        ((__bf16*)h1s)[i] = (__bf16)0.f;
        ((__bf16*)h2s)[i] = (__bf16)0.f;
    }

    // Weight B-frags, register/AGPR resident.
    // B-frag (16x16x32): lane holds B[k = kt*32 + quad*8 + j][col]
    bf16x8 W1B[3][2];
#pragma unroll
    for (int g = 0; g < 3; g++)
#pragma unroll
        for (int kt = 0; kt < 2; kt++) {
            bf16x8 a;
#pragma unroll
            for (int j = 0; j < 8; j++)
                a[j] = (__bf16)W1[(kt * 32 + quad * 8 + j) * G3 + g * 128 + u];
            W1B[g][kt] = a;
        }
    bf16x8 U1B[3][4], W2B[3][4], U2B[3][4];
#pragma unroll
    for (int g = 0; g < 3; g++)
#pragma unroll
        for (int kt = 0; kt < 4; kt++) {
            bf16x8 a, b, c;
#pragma unroll
            for (int j = 0; j < 8; j++) {
                int k = kt * 32 + quad * 8 + j;
                int col = g * 128 + u;
                a[j] = (__bf16)U1[k * G3 + col];
                b[j] = (__bf16)W2[k * G3 + col];
                c[j] = (__bf16)U2[k * G3 + col];
            }
            U1B[g][kt] = a; W2B[g][kt] = b; U2B[g][kt] = c;
        }

    // Biases (zero here, honored anyway). z/r input+recurrent biases fold.
    const float c1z  = b1[u] + b1[G3 + u];
    const float c1r  = b1[128 + u] + b1[G3 + 128 + u];
    const float b1ih = b1[256 + u];
    const float b1rh = b1[G3 + 256 + u];
    const float c2z  = b2[u] + b2[G3 + u];
    const float c2r  = b2[128 + u] + b2[G3 + 128 + u];
    const float b2ih = b2[256 + u];
    const float b2rh = b2[G3 + 256 + u];

    // x A-frag source: lane (lc,quad) owns x[row0+lc][t][kt*32+quad*8 .. +8]
    const float* xrow = x + (size_t)(row0 + lc) * (TT * FF) + quad * 8;

    // preload x(0) -> xa
    bf16x8 xa0, xa1;
    {
        f32x4 f0 = *(const f32x4*)(xrow);
        f32x4 f1 = *(const f32x4*)(xrow + 4);
        f32x4 f2 = *(const f32x4*)(xrow + 32);
        f32x4 f3 = *(const f32x4*)(xrow + 36);
#pragma unroll
        for (int j = 0; j < 4; j++) {
            xa0[j] = (__bf16)f0[j]; xa0[j + 4] = (__bf16)f1[j];
            xa1[j] = (__bf16)f2[j]; xa1[j + 4] = (__bf16)f3[j];
        }
    }

    float h1c[4] = {0.f, 0.f, 0.f, 0.f};
    float h2c[4] = {0.f, 0.f, 0.f, 0.f};

    __syncthreads();

    for (int t = 0; t < TT; t++) {
        // ph0: issue global loads for x(t+1) (consumed after ph3 -> latency hidden)
        f32x4 nf0, nf1, nf2, nf3;
        if (t + 1 < TT) {
            const float* p = xrow + (size_t)(t + 1) * FF;
            nf0 = *(const f32x4*)(p);
            nf1 = *(const f32x4*)(p + 4);
            nf2 = *(const f32x4*)(p + 32);
            nf3 = *(const f32x4*)(p + 36);
        }

        // ph1: xw1 = x(t)@W1 (+bias C-init)
        f32x4 z1  = {c1z, c1z, c1z, c1z};
        f32x4 r1  = {c1r, c1r, c1r, c1r};
        f32x4 xh1 = {b1ih, b1ih, b1ih, b1ih};
        f32x4 rh1 = {b1rh, b1rh, b1rh, b1rh};
        z1  = MFMA(xa0, W1B[0][0], z1);  z1  = MFMA(xa1, W1B[0][1], z1);
        r1  = MFMA(xa0, W1B[1][0], r1);  r1  = MFMA(xa1, W1B[1][1], r1);
        xh1 = MFMA(xa0, W1B[2][0], xh1); xh1 = MFMA(xa1, W1B[2][1], xh1);

        // ph2: layer1 recurrent, A1 = h1(t-1) (also reused by layer2 ph4!)
        bf16x8 A1[4];
#pragma unroll
        for (int kt = 0; kt < 4; kt++)
            A1[kt] = *(const bf16x8*)&h1s[(t + 1) & 1][lc][kt * 32 + quad * 8];
#pragma unroll
        for (int kt = 0; kt < 4; kt++) {
            z1  = MFMA(A1[kt], U1B[0][kt], z1);
            r1  = MFMA(A1[kt], U1B[1][kt], r1);
            rh1 = MFMA(A1[kt], U1B[2][kt], rh1);
        }

        // ph3: layer1 gates + publish h1(t)
#pragma unroll
        for (int i = 0; i < 4; i++) {
            float zf = sigf(z1[i]);
            float rf = sigf(r1[i]);
            float hh = fmaxf(xh1[i] + rf * rh1[i], 0.f);
            h1c[i] = zf * h1c[i] + (1.f - zf) * hh;
            h1s[t & 1][quad * 4 + i][u] = (__bf16)h1c[i];
        }

        // ph3.5: convert x(t+1) (global loads have drained by now); xa free after ph1
        if (t + 1 < TT) {
#pragma unroll
            for (int j = 0; j < 4; j++) {
                xa0[j] = (__bf16)nf0[j]; xa0[j + 4] = (__bf16)nf1[j];
                xa1[j] = (__bf16)nf2[j]; xa1[j + 4] = (__bf16)nf3[j];
            }
        }

        // ph4: layer2 (delayed): h2(t-1) from xw2 = h1(t-1)@W2 (A1 reuse)
        //      and rec2 = h2(t-2)@U2
        f32x4 z2  = {c2z, c2z, c2z, c2z};
        f32x4 r2  = {c2r, c2r, c2r, c2r};
        f32x4 xh2 = {b2ih, b2ih, b2ih, b2ih};
        f32x4 rh2 = {b2rh, b2rh, b2rh, b2rh};
#pragma unroll
        for (int kt = 0; kt < 4; kt++) {
            z2  = MFMA(A1[kt], W2B[0][kt], z2);
            r2  = MFMA(A1[kt], W2B[1][kt], r2);
            xh2 = MFMA(A1[kt], W2B[2][kt], xh2);
        }
        bf16x8 A2[4];
#pragma unroll
        for (int kt = 0; kt < 4; kt++)
            A2[kt] = *(const bf16x8*)&h2s[t & 1][lc][kt * 32 + quad * 8];
#pragma unroll
        for (int kt = 0; kt < 4; kt++) {
            z2  = MFMA(A2[kt], U2B[0][kt], z2);
            r2  = MFMA(A2[kt], U2B[1][kt], r2);
            rh2 = MFMA(A2[kt], U2B[2][kt], rh2);
        }
        if (t > 0) {
#pragma unroll
            for (int i = 0; i < 4; i++) {
                float zf = sigf(z2[i]);
                float rf = sigf(r2[i]);
                float hh = fmaxf(xh2[i] + rf * rh2[i], 0.f);
                h2c[i] = zf * h2c[i] + (1.f - zf) * hh;
            }
        }
#pragma unroll
        for (int i = 0; i < 4; i++)
            h2s[(t + 1) & 1][quad * 4 + i][u] = (__bf16)h2c[i];

        __syncthreads(); // the ONLY barrier per step
    }

    // Epilogue: h2(T-1) from h1(T-1) (h1s[(T-1)&1]) and h2(T-2) (h2s[T&1])
    {
        f32x4 z2  = {c2z, c2z, c2z, c2z};
        f32x4 r2  = {c2r, c2r, c2r, c2r};
        f32x4 xh2 = {b2ih, b2ih, b2ih, b2ih};
        f32x4 rh2 = {b2rh, b2rh, b2rh, b2rh};
#pragma unroll
        for (int kt = 0; kt < 4; kt++) {
            bf16x8 a1 = *(const bf16x8*)&h1s[(TT - 1) & 1][lc][kt * 32 + quad * 8];
            z2  = MFMA(a1, W2B[0][kt], z2);
            r2  = MFMA(a1, W2B[1][kt], r2);
            xh2 = MFMA(a1, W2B[2][kt], xh2);
        }
#pragma unroll
        for (int kt = 0; kt < 4; kt++) {
            bf16x8 a2 = *(const bf16x8*)&h2s[TT & 1][lc][kt * 32 + quad * 8];
            z2  = MFMA(a2, U2B[0][kt], z2);
            r2  = MFMA(a2, U2B[1][kt], r2);
            rh2 = MFMA(a2, U2B[2][kt], rh2);
        }
#pragma unroll
        for (int i = 0; i < 4; i++) {
            float zf = sigf(z2[i]);
            float rf = sigf(r2[i]);
            float hh = fmaxf(xh2[i] + rf * rh2[i], 0.f);
            h2c[i] = zf * h2c[i] + (1.f - zf) * hh;
        }
    }

    // out = [x = h2(T-1), state1 = h1(T-1), state2 = h2(T-1)]
#pragma unroll
    for (int i = 0; i < 4; i++) {
        int r = row0 + quad * 4 + i;
        out[(size_t)r * 128 + u]         = h2c[i];
        out[32768 + (size_t)r * 128 + u] = h1c[i];
        out[65536 + (size_t)r * 128 + u] = h2c[i];
    }
}

extern "C" void kernel_launch(void* const* d_in, const int* in_sizes, int n_in,
                              void* d_out, int out_size, void* d_ws, size_t ws_size,
                              hipStream_t stream) {
    const float* x  = (const float*)d_in[0];
    const float* W1 = (const float*)d_in[1];
    const float* U1 = (const float*)d_in[2];
    const float* b1 = (const float*)d_in[3];
    const float* W2 = (const float*)d_in[4];
    const float* U2 = (const float*)d_in[5];
    const float* b2 = (const float*)d_in[6];
    float* out = (float*)d_out;
    gru_fused<<<dim3(16), dim3(512), 0, stream>>>(x, W1, U1, b1, W2, U2, b2, out);
}